// Round 8
// baseline (115.666 us; speedup 1.0000x reference)
//
#include <hip/hip_runtime.h>
#include <float.h>

#define BB 16
#define MM 32
#define KK 20
#define AA 8
#define TT 30
#define TD 60          // T*D floats per trajectory
#define NS 15          // float4 steps per trajectory (2 t-steps each)
#define KT 22          // target rows: 20 real + gt (row 20) + dummy (row 21)
#define PDS 21         // pd row stride in floats
#define GRID (BB * AA * (MM / 2))   // 2048

// One block = 2 waves = 2 m's sharing the target tile, for a fixed (b, a).
// grid = 2048 -> exactly 8 blocks/CU (LDS 18.2 KB) -> 16 waves/CU, balanced.
// k-map: k = tk + 5i (tk<5); kp = tkp + 11j (tkp<11); 55 lanes cover 20x22
// (col 20 = gt, col 21 = dummy).
// Last block (atomic counter) performs the final A-mean/M-min/B-mean and
// writes d_out -- no second kernel launch.
__global__ __launch_bounds__(128, 4) void imle_part_kernel(
    const float* __restrict__ gen,   // B M K A T D
    const float* __restrict__ tgt,   // B K A T D
    const float* __restrict__ gt,    // B A T D
    float* __restrict__ ws_cham,     // [B][M][A]
    float* __restrict__ ws_gt,       // [B][M][A]
    unsigned int* __restrict__ counter,
    float* __restrict__ out)
{
    __shared__ float4 sg[2][KK][NS];   // 2 m-slices of gen, x50 (reused by finisher)
    __shared__ float4 st[KT][NS];      // target rows (x50) + gt row + dummy
    __shared__ float  pd[2][KK][PDS];  // per-m pairwise mean distances
    __shared__ int    s_last;

    const int blk = blockIdx.x;        // grid = 2048
    const int mg = blk & 15;           // m-group (M/2 = 16)
    const int a  = (blk >> 4) & 7;
    const int b  = blk >> 7;
    const int m0 = mg * 2;
    const int tid = threadIdx.x;

    // ---- stage gen: 2m x 20k rows of 15 float4 ----
    for (int idx = tid; idx < 40 * NS; idx += 128) {
        int row = idx / NS, q = idx - row * NS;
        int mi = row / KK, k = row - mi * KK;
        float4 v = ((const float4*)(gen +
            (size_t)(((b * MM + m0 + mi) * KK + k) * AA + a) * TD))[q];
        v.x *= 50.f; v.y *= 50.f; v.z *= 50.f; v.w *= 50.f;
        sg[mi][k][q] = v;
    }
    // ---- stage target rows 0..19 (x50), row 20 = gt (metric), row 21 = zeros ----
    for (int idx = tid; idx < KT * NS; idx += 128) {
        int row = idx / NS, q = idx - row * NS;
        float4 v;
        if (row < KK) {
            v = ((const float4*)(tgt + (size_t)((b * KK + row) * AA + a) * TD))[q];
            v.x *= 50.f; v.y *= 50.f; v.z *= 50.f; v.w *= 50.f;
        } else if (row == KK) {
            v = ((const float4*)(gt + (size_t)(b * AA + a) * TD))[q];
        } else {
            v = make_float4(0.f, 0.f, 0.f, 0.f);
        }
        st[row][q] = v;
    }
    __syncthreads();

    const int w = tid >> 6;        // wave id -> m offset (0 or 1)
    const int lane = tid & 63;

    // ---- pairwise distances: 4x2 register tile ----
    if (lane < 55) {
        const int tk  = lane / 11;       // k  = tk + 5i
        const int tkp = lane - tk * 11;  // kp = tkp + 11j
        float acc[4][2] = {{0.f, 0.f}, {0.f, 0.f}, {0.f, 0.f}, {0.f, 0.f}};
#pragma unroll 3
        for (int s = 0; s < NS; ++s) {
            float4 gv[4], tv[2];
#pragma unroll
            for (int i = 0; i < 4; ++i) gv[i] = sg[w][tk + 5 * i][s];
            tv[0] = st[tkp][s];
            tv[1] = st[tkp + 11][s];
#pragma unroll
            for (int i = 0; i < 4; ++i) {
#pragma unroll
                for (int j = 0; j < 2; ++j) {
                    float dx1 = gv[i].x - tv[j].x;
                    float dy1 = gv[i].y - tv[j].y;
                    float dx2 = gv[i].z - tv[j].z;
                    float dy2 = gv[i].w - tv[j].w;
                    acc[i][j] += __builtin_amdgcn_sqrtf(fmaf(dy1, dy1, dx1 * dx1))
                               + __builtin_amdgcn_sqrtf(fmaf(dy2, dy2, dx2 * dx2));
                }
            }
        }
        const float inv_t = 1.0f / TT;
#pragma unroll
        for (int i = 0; i < 4; ++i) {
            pd[w][tk + 5 * i][tkp] = acc[i][0] * inv_t;   // kp = tkp <= 10, always real
            if (tkp + 11 <= KK)                           // col 21 is dummy
                pd[w][tk + 5 * i][tkp + 11] = acc[i][1] * inv_t;
        }
    }
    __syncthreads();

    // ---- fused 40-lane row/col scan + gt column, one 64-wide butterfly ----
    const float* pdw = &pd[w][0][0];
    float v = 0.f;
    float dg = FLT_MAX;
    if (lane < 40) {
        const bool isrow = lane < 20;
        const int l = isrow ? lane : lane - 20;
        float mn = isrow ? pdw[l * PDS] : pdw[l];
#pragma unroll
        for (int j = 1; j < KK; ++j) {
            int idx = isrow ? (l * PDS + j) : (j * PDS + l);
            mn = fminf(mn, pdw[idx]);
        }
        v = mn;                       // rows: rowmin, cols: colmin
    } else if (lane < 40 + KK) {
        dg = pdw[(lane - 40) * PDS + KK];   // gt column
    }
#pragma unroll
    for (int off = 32; off > 0; off >>= 1) {
        v += __shfl_xor(v, off, 64);              // sum(rowmin) + sum(colmin)
        dg = fminf(dg, __shfl_xor(dg, off, 64));  // min over gt column
    }
    if (lane == 0) {
        const size_t o = ((size_t)b * MM + (m0 + w)) * AA + a;
        ws_cham[o] = v * (1.0f / KK);
        ws_gt[o]   = dg;
    }
    __syncthreads();   // both waves' partial stores issued (vmcnt drained)

    // ---- last-block final reduction ----
    if (tid == 0) {
        __threadfence();                            // release: wbl2 (cross-XCD)
        unsigned int old = atomicAdd(counter, 1u);  // device-scope
        s_last = (old == GRID - 1) ? 1 : 0;
    }
    __syncthreads();
    if (!s_last) return;
    __threadfence();                                // acquire: invalidate stale

    float* s_ch = (float*)&sg[0][0][0];   // reuse sg LDS (9600 B >= 4 KB)
    float* s_gv = s_ch + BB * MM;         // 512 + 512 floats
    for (int r = 0; r < 4; ++r) {
        int p = tid + r * 128;            // (b,m) pair, 0..511
        float sc = 0.f, sgv = 0.f;
#pragma unroll
        for (int a2 = 0; a2 < AA; ++a2) {
            sc  += ws_cham[(size_t)p * AA + a2];
            sgv += ws_gt[(size_t)p * AA + a2];
        }
        s_ch[p] = sc * (1.0f / AA);
        s_gv[p] = sgv * (1.0f / AA);
    }
    __syncthreads();
    float* s_mb = (float*)&pd[0][0][0];   // reuse pd LDS for per-b mins
    if (tid < BB) {
        float c = s_ch[tid * MM], g = s_gv[tid * MM];
        for (int j = 1; j < MM; ++j) {
            c = fminf(c, s_ch[tid * MM + j]);
            g = fminf(g, s_gv[tid * MM + j]);
        }
        s_mb[tid]      = c;
        s_mb[BB + tid] = g;
    }
    __syncthreads();
    if (tid == 0) {
        float lc = 0.f, lg = 0.f;
        for (int j = 0; j < BB; ++j) { lc += s_mb[j]; lg += s_mb[BB + j]; }
        lc *= (1.0f / BB);
        lg *= (1.0f / BB);
        out[0] = lc + lg;
        out[1] = lc;
        out[2] = lg;
    }
}

extern "C" void kernel_launch(void* const* d_in, const int* in_sizes, int n_in,
                              void* d_out, int out_size, void* d_ws, size_t ws_size,
                              hipStream_t stream) {
    const float* gen = (const float*)d_in[0];
    const float* tgt = (const float*)d_in[1];
    const float* gt  = (const float*)d_in[2];
    float* ws_cham = (float*)d_ws;                         // B*M*A floats
    float* ws_gt   = ws_cham + BB * MM * AA;               // B*M*A floats
    unsigned int* counter = (unsigned int*)(ws_gt + BB * MM * AA);
    float* out = (float*)d_out;

    hipMemsetAsync(counter, 0, sizeof(unsigned int), stream);  // capturable
    imle_part_kernel<<<GRID, 128, 0, stream>>>(gen, tgt, gt,
                                               ws_cham, ws_gt, counter, out);
}

// Round 9
// 89.033 us; speedup vs baseline: 1.2991x; 1.2991x over previous
//
#include <hip/hip_runtime.h>
#include <float.h>

#define BB 16
#define MM 32
#define KK 20
#define AA 8
#define TT 30
#define TD 60          // T*D floats per trajectory
#define NQ 15          // float4 per trajectory
#define WPG 11         // waves per (b,a): 10 waves x 3 m + 1 wave x 2 m
#define PDS 21         // pd innermost stride (floats)

// One block = one wave = 3 m's (lanes (mi,k) = 3x20, lanes 60-63 idle) for a
// fixed (b,a). Gen trajectory register-resident (60 VGPR/lane, unscaled).
// Target rows are wave-uniform -> compiler emits s_load (SMEM/SGPR broadcast):
// the pair loop has ZERO LDS reads and no per-lane target addressing.
// Scale folding: dist(50g,50t) = 50*dist(g,t), applied once at the epilogue.
// LDS keeps only pd[mi][kp][k] for the colmin transpose.
__global__ __launch_bounds__(64, 2) void imle_part_kernel(
    const float* __restrict__ gen,   // B M K A T D
    const float* __restrict__ tgt,   // B K A T D
    const float* __restrict__ gt,    // B A T D
    float* __restrict__ ws_cham,     // [B][M][A]
    float* __restrict__ ws_gt)       // [B][M][A]
{
    __shared__ float pd[4][KK][PDS];   // plane 3 = scratch for idle lanes
    __shared__ float red_s[3 * KK];
    __shared__ float red_g[3 * KK];

    const int blk = blockIdx.x;          // grid = BB*AA*WPG = 1408
    const int wid = blk % WPG;
    const int ba  = blk / WPG;
    const int a   = ba & 7;
    const int b   = ba >> 3;
    const int m0  = wid * 3;
    const int nm  = (m0 + 3 <= MM) ? 3 : (MM - m0);   // 3, last wave: 2

    const int lane = threadIdx.x;
    const int mi = lane / KK;            // 0..3 (3 = idle lanes 60-63)
    const int k  = lane - mi * KK;
    const bool active = (mi < nm);
    const int mi_c = active ? mi : 0;    // clamp for safe addresses

    // ---- own gen trajectory -> registers (unscaled) ----
    const float4* grow4 = (const float4*)(gen +
        (size_t)(((b * MM + m0 + mi_c) * KK + k) * AA + a) * TD);
    float4 g[NQ];
#pragma unroll
    for (int q = 0; q < NQ; ++q) g[q] = grow4[q];

    // ---- 20 target rows: SGPR-broadcast, pure-VALU distance ----
    float rowmin = FLT_MAX;
    for (int kp = 0; kp < KK; ++kp) {
        const float4* trow = (const float4*)(tgt +
            (size_t)((b * KK + kp) * AA + a) * TD);   // wave-uniform
        float acc = 0.f;
#pragma unroll
        for (int q = 0; q < NQ; ++q) {
            float4 tv = trow[q];          // s_load_dwordx4
            float dx1 = g[q].x - tv.x;
            float dy1 = g[q].y - tv.y;
            float dx2 = g[q].z - tv.z;
            float dy2 = g[q].w - tv.w;
            acc += __builtin_amdgcn_sqrtf(fmaf(dy1, dy1, dx1 * dx1))
                 + __builtin_amdgcn_sqrtf(fmaf(dy2, dy2, dx2 * dx2));
        }
        rowmin = fminf(rowmin, acc);      // min over kp (raw units)
        pd[mi][kp][k] = acc;              // [kp][k]: colmin scans are contiguous
    }

    // ---- gt row (metric): scale gen x50 on the fly ----
    float dgt;
    {
        const float4* qrow = (const float4*)(gt + (size_t)(b * AA + a) * TD);
        float acc = 0.f;
#pragma unroll
        for (int q = 0; q < NQ; ++q) {
            float4 tv = qrow[q];
            float dx1 = g[q].x * 50.f - tv.x;
            float dy1 = g[q].y * 50.f - tv.y;
            float dx2 = g[q].z * 50.f - tv.z;
            float dy2 = g[q].w * 50.f - tv.w;
            acc += __builtin_amdgcn_sqrtf(fmaf(dy1, dy1, dx1 * dx1))
                 + __builtin_amdgcn_sqrtf(fmaf(dy2, dy2, dx2 * dx2));
        }
        dgt = acc * (1.0f / TT);          // metric mean over T
    }
    __syncthreads();

    // ---- colmin: lane (mi, j=k) scans pd[mi][j][0..19] (min over gen-k) ----
    float colmin = FLT_MAX;
    if (active) {
        const float* prow = &pd[mi][k][0];
        colmin = prow[0];
#pragma unroll
        for (int x = 1; x < KK; ++x) colmin = fminf(colmin, prow[x]);
        red_s[mi * KK + k] = rowmin + colmin;   // raw units
        red_g[mi * KK + k] = dgt;
    }
    __syncthreads();

    // ---- per-m finish: sum(rowmin)+sum(colmin), min(dgt) over the 20-group ----
    if (lane < nm) {
        float s = 0.f, gm = FLT_MAX;
        for (int x = 0; x < KK; ++x) {
            s += red_s[lane * KK + x];
            gm = fminf(gm, red_g[lane * KK + x]);
        }
        const size_t o = ((size_t)b * MM + (m0 + lane)) * AA + a;
        ws_cham[o] = s * (50.0f / (TT * KK));   // x50 scale, /30 T-mean, /20 K-mean
        ws_gt[o]   = gm;
    }
}

// Single block: mean over A, min over M, mean over B, write 3 outputs.
__global__ __launch_bounds__(512) void imle_final_kernel(
    const float* __restrict__ ws_cham,
    const float* __restrict__ ws_gt,
    float* __restrict__ out)
{
    __shared__ float ch[BB * MM], gv[BB * MM];
    __shared__ float mch[BB], mgt[BB];
    const int tid = threadIdx.x;  // 512 == B*M
    const int b = tid / MM, m = tid % MM;

    float sc = 0.f, sg = 0.f;
#pragma unroll
    for (int a = 0; a < AA; ++a) {
        sc += ws_cham[((size_t)b * MM + m) * AA + a];
        sg += ws_gt[((size_t)b * MM + m) * AA + a];
    }
    ch[tid] = sc * (1.0f / AA);
    gv[tid] = sg * (1.0f / AA);
    __syncthreads();

    if (tid < BB) {
        float c = ch[tid * MM], g = gv[tid * MM];
        for (int j = 1; j < MM; ++j) {
            c = fminf(c, ch[tid * MM + j]);
            g = fminf(g, gv[tid * MM + j]);
        }
        mch[tid] = c;
        mgt[tid] = g;
    }
    __syncthreads();

    if (tid == 0) {
        float lc = 0.f, lg = 0.f;
        for (int j = 0; j < BB; ++j) { lc += mch[j]; lg += mgt[j]; }
        lc *= (1.0f / BB);
        lg *= (1.0f / BB);
        out[0] = lc + lg;
        out[1] = lc;
        out[2] = lg;
    }
}

extern "C" void kernel_launch(void* const* d_in, const int* in_sizes, int n_in,
                              void* d_out, int out_size, void* d_ws, size_t ws_size,
                              hipStream_t stream) {
    const float* gen = (const float*)d_in[0];
    const float* tgt = (const float*)d_in[1];
    const float* gt  = (const float*)d_in[2];
    float* ws_cham = (float*)d_ws;                 // B*M*A floats
    float* ws_gt   = ws_cham + BB * MM * AA;       // B*M*A floats
    float* out     = (float*)d_out;

    imle_part_kernel<<<BB * AA * WPG, 64, 0, stream>>>(gen, tgt, gt, ws_cham, ws_gt);
    imle_final_kernel<<<1, 512, 0, stream>>>(ws_cham, ws_gt, out);
}

// Round 10
// 86.437 us; speedup vs baseline: 1.3382x; 1.0300x over previous
//
#include <hip/hip_runtime.h>
#include <float.h>

#define BB 16
#define MM 32
#define KK 20
#define AA 8
#define TT 30
#define TD 60          // T*D floats per trajectory
#define NQ 15          // float4 per trajectory
#define WPG 11         // m-groups per (b,a): 10 x 3m + 1 x 2m
#define PDS 21         // pd innermost stride (floats)

// One block = 4 waves, all covering the same 3 m's of a fixed (b,a).
// Wave w handles target rows kp in [5w, 5w+5) -> 5632 waves = 5.5 waves/SIMD
// (4x R9's 1.4 -- R9 proved the zero-LDS loop but starved the scheduler).
// Lanes = (mi,k) = 3x20 (60 active). Gen trajectory register-resident
// (60 VGPR, unscaled; dist scales fold: dist(50g,50t)=50*dist(g,t)).
// Target-row pointers are wave-uniform (readfirstlane forces the compiler's
// uniformity analysis) -> s_load_dwordx4 SGPR broadcast, zero LDS in the loop.
__global__ __launch_bounds__(256, 5) void imle_part_kernel(
    const float* __restrict__ gen,   // B M K A T D
    const float* __restrict__ tgt,   // B K A T D
    const float* __restrict__ gt,    // B A T D
    float* __restrict__ ws_cham,     // [B][M][A]
    float* __restrict__ ws_gt)       // [B][M][A]
{
    __shared__ float pd[3][KK][PDS];   // pd[mi][kp][k], complete after barrier
    __shared__ float rmw[4][3][KK];    // per-wave kp-subset rowmins
    __shared__ float red_s[3 * KK];
    __shared__ float red_g[3 * KK];

    const int blk = blockIdx.x;          // grid = BB*AA*WPG = 1408
    const int wid = blk % WPG;
    const int ba  = blk / WPG;
    const int a   = ba & 7;
    const int b   = ba >> 3;
    const int m0  = wid * 3;
    const int nm  = (m0 + 3 <= MM) ? 3 : (MM - m0);   // 3, last group: 2

    const int tid  = threadIdx.x;
    // force wave-uniform scalar: compiler treats tid-derived values as
    // divergent, which would demote the target loads to per-lane VMEM.
    const int ww   = __builtin_amdgcn_readfirstlane(tid >> 6);
    const int lane = tid & 63;
    const int mi = lane / KK;            // 0..3 (3 = idle lanes 60-63)
    const int k  = lane - mi * KK;
    const bool active = (mi < nm);
    const int mi_c = active ? mi : 0;    // clamp for safe addresses

    // ---- own gen trajectory -> registers (unscaled) ----
    const float4* grow4 = (const float4*)(gen +
        (size_t)(((b * MM + m0 + mi_c) * KK + k) * AA + a) * TD);
    float4 g[NQ];
#pragma unroll
    for (int q = 0; q < NQ; ++q) g[q] = grow4[q];

    // ---- this wave's 5 target rows: SGPR-broadcast, pure-VALU distance ----
    const int kp0 = 5 * ww;
    float rowmin = FLT_MAX;
#pragma unroll
    for (int kp2 = 0; kp2 < 5; ++kp2) {
        const int kp = kp0 + kp2;
        const float4* trow = (const float4*)(tgt +
            (size_t)((b * KK + kp) * AA + a) * TD);   // wave-uniform
        float acc = 0.f;
#pragma unroll
        for (int q = 0; q < NQ; ++q) {
            float4 tv = trow[q];          // s_load_dwordx4
            float dx1 = g[q].x - tv.x;
            float dy1 = g[q].y - tv.y;
            float dx2 = g[q].z - tv.z;
            float dy2 = g[q].w - tv.w;
            acc += __builtin_amdgcn_sqrtf(fmaf(dy1, dy1, dx1 * dx1))
                 + __builtin_amdgcn_sqrtf(fmaf(dy2, dy2, dx2 * dx2));
        }
        rowmin = fminf(rowmin, acc);      // min over this wave's kp subset
        if (active) pd[mi][kp][k] = acc;
    }
    if (active) rmw[ww][mi][k] = rowmin;

    // ---- gt row (metric, x50 on the fly): wave 0 only ----
    float dgt = FLT_MAX;
    if (ww == 0) {
        const float4* qrow = (const float4*)(gt + (size_t)(b * AA + a) * TD);
        float acc = 0.f;
#pragma unroll
        for (int q = 0; q < NQ; ++q) {
            float4 tv = qrow[q];
            float dx1 = g[q].x * 50.f - tv.x;
            float dy1 = g[q].y * 50.f - tv.y;
            float dx2 = g[q].z * 50.f - tv.z;
            float dy2 = g[q].w * 50.f - tv.w;
            acc += __builtin_amdgcn_sqrtf(fmaf(dy1, dy1, dx1 * dx1))
                 + __builtin_amdgcn_sqrtf(fmaf(dy2, dy2, dx2 * dx2));
        }
        dgt = acc * (1.0f / TT);          // metric mean over T
    }
    __syncthreads();

    // ---- wave 0: combine rowmins, colmin scan, per-(mi,k) partials ----
    if (ww == 0 && active) {
        float rm = fminf(fminf(rmw[0][mi][k], rmw[1][mi][k]),
                         fminf(rmw[2][mi][k], rmw[3][mi][k]));
        const float* prow = &pd[mi][k][0];        // fixed kp=k, scan gen index
        float colmin = prow[0];
#pragma unroll
        for (int x = 1; x < KK; ++x) colmin = fminf(colmin, prow[x]);
        red_s[mi * KK + k] = rm + colmin;         // raw units
        red_g[mi * KK + k] = dgt;
    }
    __syncthreads();

    // ---- per-m finish: sum partials, min(dgt) over the 20-group ----
    if (tid < nm) {
        float s = 0.f, gm = FLT_MAX;
        for (int x = 0; x < KK; ++x) {
            s += red_s[tid * KK + x];
            gm = fminf(gm, red_g[tid * KK + x]);
        }
        const size_t o = ((size_t)b * MM + (m0 + tid)) * AA + a;
        ws_cham[o] = s * (50.0f / (TT * KK));   // x50 scale, /30 T-mean, /20 K-mean
        ws_gt[o]   = gm;
    }
}

// Single block: mean over A, min over M, mean over B, write 3 outputs.
__global__ __launch_bounds__(512) void imle_final_kernel(
    const float* __restrict__ ws_cham,
    const float* __restrict__ ws_gt,
    float* __restrict__ out)
{
    __shared__ float ch[BB * MM], gv[BB * MM];
    __shared__ float mch[BB], mgt[BB];
    const int tid = threadIdx.x;  // 512 == B*M
    const int b = tid / MM, m = tid % MM;

    float sc = 0.f, sg = 0.f;
#pragma unroll
    for (int a = 0; a < AA; ++a) {
        sc += ws_cham[((size_t)b * MM + m) * AA + a];
        sg += ws_gt[((size_t)b * MM + m) * AA + a];
    }
    ch[tid] = sc * (1.0f / AA);
    gv[tid] = sg * (1.0f / AA);
    __syncthreads();

    if (tid < BB) {
        float c = ch[tid * MM], g = gv[tid * MM];
        for (int j = 1; j < MM; ++j) {
            c = fminf(c, ch[tid * MM + j]);
            g = fminf(g, gv[tid * MM + j]);
        }
        mch[tid] = c;
        mgt[tid] = g;
    }
    __syncthreads();

    if (tid == 0) {
        float lc = 0.f, lg = 0.f;
        for (int j = 0; j < BB; ++j) { lc += mch[j]; lg += mgt[j]; }
        lc *= (1.0f / BB);
        lg *= (1.0f / BB);
        out[0] = lc + lg;
        out[1] = lc;
        out[2] = lg;
    }
}

extern "C" void kernel_launch(void* const* d_in, const int* in_sizes, int n_in,
                              void* d_out, int out_size, void* d_ws, size_t ws_size,
                              hipStream_t stream) {
    const float* gen = (const float*)d_in[0];
    const float* tgt = (const float*)d_in[1];
    const float* gt  = (const float*)d_in[2];
    float* ws_cham = (float*)d_ws;                 // B*M*A floats
    float* ws_gt   = ws_cham + BB * MM * AA;       // B*M*A floats
    float* out     = (float*)d_out;

    imle_part_kernel<<<BB * AA * WPG, 256, 0, stream>>>(gen, tgt, gt, ws_cham, ws_gt);
    imle_final_kernel<<<1, 512, 0, stream>>>(ws_cham, ws_gt, out);
}

// Round 11
// 83.785 us; speedup vs baseline: 1.3805x; 1.0317x over previous
//
#include <hip/hip_runtime.h>
#include <float.h>

#define BB 16
#define MM 32
#define KK 20
#define AA 8
#define TT 30
#define TD 60          // T*D floats per trajectory
#define NQ 15          // float4 per trajectory
#define WPG 11         // m-groups per (b,a): 10 x 3m + 1 x 2m
#define PDS 21         // pd innermost stride (floats)

// One block = 4 waves over the same 3 m's of a fixed (b,a); wave w handles
// target rows kp ≡ w (mod 4) -> 5 rows each. Lanes = (mi,k) = 3x20; lanes
// 60-63 alias (0, 0..3) and redundantly compute identical values (benign
// duplicate LDS writes) -> the distance phase is 100% branchless.
// Gen trajectory is register-resident (60 VGPR, direct global load, L2/L3
// absorbs the 4x wave redundancy). Target rows are wave-uniform pointers ->
// s_load SGPR broadcast; kp loop is `unroll 1` so only ONE row (~60 SGPRs)
// is live at a time (R10 fully unrolled -> 300 SGPRs -> spill/demotion).
// Distance phase uses ZERO LDS; LDS only carries pd + tiny reduction bufs.
__global__ __launch_bounds__(256, 5) void imle_part_kernel(
    const float* __restrict__ gen,   // B M K A T D
    const float* __restrict__ tgt,   // B K A T D
    const float* __restrict__ gt,    // B A T D
    float* __restrict__ ws_cham,     // [B][M][A]
    float* __restrict__ ws_gt)       // [B][M][A]
{
    __shared__ float pd[3][KK][PDS];   // [mi][kp][gen_k]
    __shared__ float rmw[4][3][KK];    // per-wave rowmin over its kp subset
    __shared__ float red_s[3 * KK];    // rowmin+colmin partials
    __shared__ float red_g[3 * KK];    // gt distances

    const int blk = blockIdx.x;          // grid = BB*AA*WPG = 1408
    const int wid = blk % WPG;
    const int ba  = blk / WPG;
    const int a   = ba & 7;
    const int b   = ba >> 3;
    const int m0  = wid * 3;
    const int nm  = (m0 + 3 <= MM) ? 3 : (MM - m0);   // 3, last group: 2

    const int tid  = threadIdx.x;
    const int ww   = __builtin_amdgcn_readfirstlane(tid >> 6);  // wave id, scalar
    const int lane = tid & 63;
    int mi = lane / KK;                  // 0..3
    const int k = lane % KK;
    if (mi == 3) mi = 0;                 // idle lanes alias (0, 0..3)
    int mi_src = mi;
    if (m0 + mi_src >= MM) mi_src = 0;   // last group's mi=2 aliases mi=0

    // ---- own gen trajectory -> registers (unscaled; scale folds to epilogue) ----
    const float4* grow4 = (const float4*)(gen +
        (size_t)(((b * MM + m0 + mi_src) * KK + k) * AA + a) * TD);
    float4 g[NQ];
#pragma unroll
    for (int q = 0; q < NQ; ++q) g[q] = grow4[q];

    // ---- 5 target rows (kp ≡ ww mod 4): SGPR broadcast, pure VALU, no LDS ----
    float rowmin = FLT_MAX;
#pragma unroll 1
    for (int kp = ww; kp < KK; kp += 4) {
        const float4* trow = (const float4*)(tgt +
            (size_t)((b * KK + kp) * AA + a) * TD);   // wave-uniform -> s_load
        float acc0 = 0.f, acc1 = 0.f;                 // 2 chains halve dep latency
#pragma unroll
        for (int q = 0; q < NQ; ++q) {
            float4 tv = trow[q];
            float dx1 = g[q].x - tv.x;
            float dy1 = g[q].y - tv.y;
            float dx2 = g[q].z - tv.z;
            float dy2 = g[q].w - tv.w;
            acc0 += __builtin_amdgcn_sqrtf(fmaf(dy1, dy1, dx1 * dx1));
            acc1 += __builtin_amdgcn_sqrtf(fmaf(dy2, dy2, dx2 * dx2));
        }
        const float acc = acc0 + acc1;
        rowmin = fminf(rowmin, acc);
        pd[mi][kp][k] = acc;             // idle lanes: duplicate value, benign
    }
    rmw[ww][mi][k] = rowmin;

    // ---- gt row (metric, x50 on the fly): wave 1 ----
    if (ww == 1) {
        const float4* qrow = (const float4*)(gt + (size_t)(b * AA + a) * TD);
        float acc0 = 0.f, acc1 = 0.f;
#pragma unroll
        for (int q = 0; q < NQ; ++q) {
            float4 tv = qrow[q];
            float dx1 = g[q].x * 50.f - tv.x;
            float dy1 = g[q].y * 50.f - tv.y;
            float dx2 = g[q].z * 50.f - tv.z;
            float dy2 = g[q].w * 50.f - tv.w;
            acc0 += __builtin_amdgcn_sqrtf(fmaf(dy1, dy1, dx1 * dx1));
            acc1 += __builtin_amdgcn_sqrtf(fmaf(dy2, dy2, dx2 * dx2));
        }
        red_g[mi * KK + k] = (acc0 + acc1) * (1.0f / TT);
    }
    __syncthreads();

    // ---- wave 0: combine rowmins + colmin scan (fixed kp=k, scan gen index) ----
    if (ww == 0) {
        float rm = fminf(fminf(rmw[0][mi][k], rmw[1][mi][k]),
                         fminf(rmw[2][mi][k], rmw[3][mi][k]));
        const float* prow = &pd[mi][k][0];
        float colmin = prow[0];
#pragma unroll
        for (int x = 1; x < KK; ++x) colmin = fminf(colmin, prow[x]);
        red_s[mi * KK + k] = rm + colmin;     // raw units
    }
    __syncthreads();

    // ---- per-m finish ----
    if (tid < nm) {
        float s = 0.f, gm = FLT_MAX;
        for (int x = 0; x < KK; ++x) {
            s += red_s[tid * KK + x];
            gm = fminf(gm, red_g[tid * KK + x]);
        }
        const size_t o = ((size_t)b * MM + (m0 + tid)) * AA + a;
        ws_cham[o] = s * (50.0f / (TT * KK));   // x50 scale, /30 T-mean, /20 K-mean
        ws_gt[o]   = gm;
    }
}

// Single block: mean over A, min over M, mean over B, write 3 outputs.
__global__ __launch_bounds__(512) void imle_final_kernel(
    const float* __restrict__ ws_cham,
    const float* __restrict__ ws_gt,
    float* __restrict__ out)
{
    __shared__ float ch[BB * MM], gv[BB * MM];
    __shared__ float mch[BB], mgt[BB];
    const int tid = threadIdx.x;  // 512 == B*M
    const int b = tid / MM, m = tid % MM;

    float sc = 0.f, sg = 0.f;
#pragma unroll
    for (int a = 0; a < AA; ++a) {
        sc += ws_cham[((size_t)b * MM + m) * AA + a];
        sg += ws_gt[((size_t)b * MM + m) * AA + a];
    }
    ch[tid] = sc * (1.0f / AA);
    gv[tid] = sg * (1.0f / AA);
    __syncthreads();

    if (tid < BB) {
        float c = ch[tid * MM], g = gv[tid * MM];
        for (int j = 1; j < MM; ++j) {
            c = fminf(c, ch[tid * MM + j]);
            g = fminf(g, gv[tid * MM + j]);
        }
        mch[tid] = c;
        mgt[tid] = g;
    }
    __syncthreads();

    if (tid == 0) {
        float lc = 0.f, lg = 0.f;
        for (int j = 0; j < BB; ++j) { lc += mch[j]; lg += mgt[j]; }
        lc *= (1.0f / BB);
        lg *= (1.0f / BB);
        out[0] = lc + lg;
        out[1] = lc;
        out[2] = lg;
    }
}

extern "C" void kernel_launch(void* const* d_in, const int* in_sizes, int n_in,
                              void* d_out, int out_size, void* d_ws, size_t ws_size,
                              hipStream_t stream) {
    const float* gen = (const float*)d_in[0];
    const float* tgt = (const float*)d_in[1];
    const float* gt  = (const float*)d_in[2];
    float* ws_cham = (float*)d_ws;                 // B*M*A floats
    float* ws_gt   = ws_cham + BB * MM * AA;       // B*M*A floats
    float* out     = (float*)d_out;

    imle_part_kernel<<<BB * AA * WPG, 256, 0, stream>>>(gen, tgt, gt, ws_cham, ws_gt);
    imle_final_kernel<<<1, 512, 0, stream>>>(ws_cham, ws_gt, out);
}